// Round 1
// baseline (540.071 us; speedup 1.0000x reference)
//
#include <hip/hip_runtime.h>
#include <math.h>

#define NROWS 200000
#define C 384
#define G 383
#define M 384          // G + 1
#define EPS 1e-5f
#define SQRTC 19.595917942265423f   // sqrt(384)

// ---------------- workspace layout (floats) ----------------
// [0 .. 383]      g_cnt   (group row counts, as float)
// [384 .. 767]    g_sum
// [768 .. 1151]   g_ss
// [1152]          acc     (global scalar accumulator for triple sum)
// [1153 .. 1536]  proto
// [1537 .. 1920]  stdv
#define WS_CNT   0
#define WS_SUM   384
#define WS_SS    768
#define WS_ACC   1152
#define WS_PROTO 1153
#define WS_STD   1537
#define WS_ZERO_FLOATS 1153   // cnt+sum+ss+acc must be zeroed each call

// K1: per-row sum / sumsq, wave-reduced, atomically accumulated per group.
__global__ void group_stats_kernel(const float* __restrict__ pred,
                                   const int* __restrict__ tgt,
                                   float* __restrict__ ws,
                                   int n_rows) {
    const int lane    = threadIdx.x & 63;
    const int wave_id = (blockIdx.x * blockDim.x + threadIdx.x) >> 6;
    const int n_waves = (gridDim.x * blockDim.x) >> 6;

    float* g_cnt = ws + WS_CNT;
    float* g_sum = ws + WS_SUM;
    float* g_ss  = ws + WS_SS;

    for (int row = wave_id; row < n_rows; row += n_waves) {
        const float* rp = pred + (size_t)row * C;
        float s = 0.f, q = 0.f;
#pragma unroll
        for (int k = 0; k < 3; ++k) {
            float2 v = *(const float2*)(rp + 2 * lane + 128 * k);
            s += v.x + v.y;
            q += v.x * v.x + v.y * v.y;
        }
        // 64-lane wave reduction
#pragma unroll
        for (int off = 32; off > 0; off >>= 1) {
            s += __shfl_down(s, off);
            q += __shfl_down(q, off);
        }
        if (lane == 0) {
            int seg = tgt[row];
            atomicAdd(&g_cnt[seg], 1.0f);
            atomicAdd(&g_sum[seg], s);
            atomicAdd(&g_ss[seg], q);
        }
    }
}

// K2: finalize per-group mean/std into proto/stdv (incl. zero pad slot).
__global__ void finalize_stats_kernel(float* __restrict__ ws) {
    int g = threadIdx.x;           // blockDim.x == M == 384
    float mean = 0.f, sd = 0.f;
    if (g < G) {
        float nr = ws[WS_CNT + g];
        if (nr > 0.5f) {
            float cnt = nr * (float)C;
            mean = ws[WS_SUM + g] / cnt;
            if (nr > 1.5f) {
                float ss = ws[WS_SS + g] - cnt * mean * mean;
                float denom = fmaxf(cnt - 1.0f, 1.0f);
                sd = sqrtf(fmaxf(ss / denom, 0.f));
            }
        }
    }
    ws[WS_PROTO + g] = mean;
    ws[WS_STD + g]   = sd;
}

// K3: one thread per (x,a); sum over b>a of s/(norm_ab + s + EPS).
__global__ void triple_sum_kernel(const float* __restrict__ ws,
                                  float* __restrict__ acc) {
    __shared__ float sp[M];
    __shared__ float sst[M];
    __shared__ float wsum[4];
    const int tid = threadIdx.x;

    for (int i = tid; i < M; i += blockDim.x) {
        sp[i]  = ws[WS_PROTO + i];
        sst[i] = ws[WS_STD + i];
    }
    __syncthreads();

    const int idx = blockIdx.x * blockDim.x + tid;   // idx = x*M + a, grid covers exactly M*M
    float partial = 0.f;
    if (idx < M * M) {
        const int x = idx / M;
        const int a = idx - x * M;
        const float pa = sp[a];
        const float u  = fabsf(pa - sp[x]);
        const float t  = u / (u * SQRTC + EPS);      // |d[x,a]|
        if (t > 0.f) {
            const float sa = sst[a];
            for (int b = a + 1; b < M; ++b) {
                float nab = fabsf(sp[b] - pa) * SQRTC;
                float s   = t * (sa + sst[b]);
                partial += s * __builtin_amdgcn_rcpf(nab + s + EPS);
            }
        }
    }

    // block reduction: wave shuffle + cross-wave LDS
#pragma unroll
    for (int off = 32; off > 0; off >>= 1)
        partial += __shfl_down(partial, off);
    if ((tid & 63) == 0) wsum[tid >> 6] = partial;
    __syncthreads();
    if (tid == 0) {
        float b0 = wsum[0] + wsum[1] + wsum[2] + wsum[3];
        atomicAdd(acc, b0);
    }
}

// K4: scale and write output.
__global__ void write_out_kernel(const float* __restrict__ ws,
                                 float* __restrict__ out) {
    out[0] = ws[WS_ACC] / ((float)M * (float)M * (float)M);
}

extern "C" void kernel_launch(void* const* d_in, const int* in_sizes, int n_in,
                              void* d_out, int out_size, void* d_ws, size_t ws_size,
                              hipStream_t stream) {
    const float* pred = (const float*)d_in[0];
    const int*   tgt  = (const int*)d_in[1];
    float* ws  = (float*)d_ws;
    float* out = (float*)d_out;
    const int n_rows = in_sizes[1];

    hipMemsetAsync(ws, 0, WS_ZERO_FLOATS * sizeof(float), stream);

    // K1: 2048 blocks x 256 threads = 8192 waves, grid-stride over rows
    group_stats_kernel<<<2048, 256, 0, stream>>>(pred, tgt, ws, n_rows);

    // K2: one block over all M slots
    finalize_stats_kernel<<<1, M, 0, stream>>>(ws);

    // K3: M*M threads total = 576 blocks of 256
    triple_sum_kernel<<<(M * M) / 256, 256, 0, stream>>>(ws, ws + WS_ACC);

    // K4
    write_out_kernel<<<1, 1, 0, stream>>>(ws, out);
}